// Round 2
// baseline (616.829 us; speedup 1.0000x reference)
//
#include <hip/hip_runtime.h>
#include <math.h>

// Topology: x(256,256,64,25) -> T-mean -> center over C -> cov(25x25)
// -> bimap W1,W2,W3 (ReEig = identity: eigenvalues >= ~0.0074 >> 1e-4)
// -> logeig(10x10 via Jacobi) -> FC(100->64).
//
// 3-kernel split:
//   k_tsum: streaming T-reduction (419MB -> 6.5MB ws), 2048 blocks, BW-bound.
//   k_cov : per-n centering + Wc + E + M(10x10) -> ws. 256 blocks x 256.
//   k_eig : per-n Jacobi + logeig + FC. 256 blocks x 64 threads = ONE WAVE,
//           so the 216 __syncthreads in the Jacobi loop are ~free (1-wave
//           barriers complete immediately). This removes the multi-wave
//           barrier tax that dominated the fused kernel.

__device__ __constant__ int d_pairs[9][5][2] = {
    {{9,0},{1,8},{2,7},{3,6},{4,5}},
    {{9,1},{2,0},{3,8},{4,7},{5,6}},
    {{9,2},{3,1},{4,0},{5,8},{6,7}},
    {{9,3},{4,2},{5,1},{6,0},{7,8}},
    {{9,4},{5,3},{6,2},{7,1},{8,0}},
    {{9,5},{6,4},{7,3},{8,2},{0,1}},
    {{9,6},{7,5},{8,4},{0,3},{1,2}},
    {{9,7},{8,6},{0,5},{1,4},{2,3}},
    {{9,8},{0,7},{1,6},{2,5},{3,4}},
};

// ---------------------------------------------------------------------------
// K1: xsum[row][v] = sum_t x[row][t][v], row = n*256+c (65536 rows of 1600).
// task = (r, m): float4 phase m of row r; element e = 4m+i+100k has fixed
// v = (4m+i) mod 25, so 4 register sums -> 4 LDS atomics per task.
__global__ __launch_bounds__(256) void k_tsum(
    const float* __restrict__ x, float* __restrict__ xsum)
{
    __shared__ float s_sum[800];   // 32 rows x 25
    const int tid = threadIdx.x;
    const size_t row0 = (size_t)blockIdx.x * 32;

    for (int g = tid; g < 800; g += 256) s_sum[g] = 0.0f;
    __syncthreads();

    const float4* base = reinterpret_cast<const float4*>(x) + row0 * 400;
    for (int task = tid; task < 800; task += 256) {
        int r = task / 25, m = task - r * 25;
        const float4* p = base + r * 400 + m;
        float s0 = 0.0f, s1 = 0.0f, s2 = 0.0f, s3 = 0.0f;
#pragma unroll
        for (int k = 0; k < 16; ++k) {
            float4 vv = p[25 * k];
            s0 += vv.x; s1 += vv.y; s2 += vv.z; s3 += vv.w;
        }
        int v = (4 * m) % 25;
        int b = r * 25;
        atomicAdd(&s_sum[b + v], s0); v = (v + 1 == 25) ? 0 : v + 1;
        atomicAdd(&s_sum[b + v], s1); v = (v + 1 == 25) ? 0 : v + 1;
        atomicAdd(&s_sum[b + v], s2); v = (v + 1 == 25) ? 0 : v + 1;
        atomicAdd(&s_sum[b + v], s3);
    }
    __syncthreads();

    float* o = xsum + row0 * 25;
    for (int g = tid; g < 800; g += 256) o[g] = s_sum[g];
}

// ---------------------------------------------------------------------------
// K2: per n: center (mean over c), Wc = W1@W2@W3, E = d@Wc, M = E^T E/255
//     + 1e-8 Wc^T Wc. Writes M (100 floats) to ws.
__global__ __launch_bounds__(256) void k_cov(
    const float* __restrict__ xsum,
    const float* __restrict__ W1, const float* __restrict__ W2,
    const float* __restrict__ W3, float* __restrict__ Mout)
{
    __shared__ float s_xm[6400];
    __shared__ float s_mean[32];
    __shared__ float s_w1[500];
    __shared__ float s_w2[300];
    __shared__ float s_w3[152];
    __shared__ float s_t1[375];
    __shared__ float s_wc[250];
    __shared__ float s_E[2560];
    __shared__ float s_A[100];

    const int tid = threadIdx.x;
    const int n = blockIdx.x;
    const float4* xs4 = reinterpret_cast<const float4*>(xsum + (size_t)n * 6400);
    float4* sm4 = reinterpret_cast<float4*>(s_xm);
    for (int g = tid; g < 1600; g += 256) sm4[g] = xs4[g];
    for (int g = tid; g < 500; g += 256) s_w1[g] = W1[g];
    for (int g = tid; g < 300; g += 256) s_w2[g] = W2[g];
    if (tid < 150) s_w3[tid] = W3[tid];
    __syncthreads();

    // T1 = W1@W2 ; column sums -> mean (sum/(64*256))
    for (int g = tid; g < 375; g += 256) {
        int i = g / 15, l = g - i * 15;
        float s = 0.0f;
#pragma unroll
        for (int j = 0; j < 20; ++j) s += s_w1[i * 20 + j] * s_w2[j * 15 + l];
        s_t1[g] = s;
    }
    if (tid < 25) {
        float s = 0.0f;
        for (int c = 0; c < 256; ++c) s += s_xm[c * 25 + tid];
        s_mean[tid] = s * (1.0f / (64.0f * 256.0f));
    }
    __syncthreads();

    // Wc = T1@W3 ; center+scale: d = sum/64 - mean
    for (int g = tid; g < 250; g += 256) {
        int i = g / 10, m = g - i * 10;
        float s = 0.0f;
#pragma unroll
        for (int l = 0; l < 15; ++l) s += s_t1[i * 15 + l] * s_w3[l * 10 + m];
        s_wc[g] = s;
    }
    __syncthreads();
    for (int o = tid; o < 6400; o += 256) {
        int v = o - (o / 25) * 25;
        s_xm[o] = s_xm[o] * (1.0f / 64.0f) - s_mean[v];
    }
    __syncthreads();

    // E = d @ Wc  (256x10)
    for (int idx = tid; idx < 2560; idx += 256) {
        int c = idx / 10, i = idx - (idx / 10) * 10;
        float s = 0.0f;
#pragma unroll
        for (int v = 0; v < 25; ++v) s += s_xm[c * 25 + v] * s_wc[v * 10 + i];
        s_E[idx] = s;
    }
    __syncthreads();

    // M = E^T E / 255 + 1e-8 * Wc^T Wc
    if (tid < 55) {
        int i = 0, rem = tid;
        while (rem >= 10 - i) { rem -= 10 - i; ++i; }
        int j = i + rem;
        float s = 0.0f;
        for (int c = 0; c < 256; ++c) s += s_E[c * 10 + i] * s_E[c * 10 + j];
        float wt = 0.0f;
#pragma unroll
        for (int v = 0; v < 25; ++v) wt += s_wc[v * 10 + i] * s_wc[v * 10 + j];
        float m = s * (1.0f / 255.0f) + 1e-8f * wt;
        s_A[i * 10 + j] = m;
        s_A[j * 10 + i] = m;
    }
    __syncthreads();
    if (tid < 100) Mout[(size_t)n * 100 + tid] = s_A[tid];
}

// ---------------------------------------------------------------------------
// K3: per n (single wave): Jacobi eigensolve of 10x10, logeig, FC(100->64).
__global__ __launch_bounds__(64) void k_eig(
    const float* __restrict__ Min,
    const float* __restrict__ fcw, const float* __restrict__ fcb,
    float* __restrict__ out)
{
    __shared__ float s_A[100];
    __shared__ float s_U[100];
    __shared__ float s_cp[10], s_cq[10];
    __shared__ int   s_ip[10], s_iq[10];
    __shared__ float s_lw[16];
    __shared__ float s_Y[100];
    __shared__ float s_fcw[100 * 65];   // transposed, padded ld=65

    const int tid = threadIdx.x;
    const int n = blockIdx.x;

    // stage fc_w transposed via float4 (row o is 100 floats = 25 float4)
    {
        const float4* fw4 = reinterpret_cast<const float4*>(fcw);
        for (int g4 = tid; g4 < 1600; g4 += 64) {
            float4 w = fw4[g4];
            int o = g4 / 25, k4 = (g4 - o * 25) * 4;
            s_fcw[(k4 + 0) * 65 + o] = w.x;
            s_fcw[(k4 + 1) * 65 + o] = w.y;
            s_fcw[(k4 + 2) * 65 + o] = w.z;
            s_fcw[(k4 + 3) * 65 + o] = w.w;
        }
    }
    const float* Mn = Min + (size_t)n * 100;
    s_A[tid] = Mn[tid];
    if (tid < 36) s_A[tid + 64] = Mn[tid + 64];
    s_U[tid] = ((tid / 10) == (tid % 10)) ? 1.0f : 0.0f;
    if (tid < 36) {
        int e = tid + 64;
        s_U[e] = ((e / 10) == (e % 10)) ? 1.0f : 0.0f;
    }
    __syncthreads();

    // Jacobi (tournament order, 8 sweeps). 1-wave block: barriers are ~free.
    for (int sweep = 0; sweep < 8; ++sweep) {
        for (int r = 0; r < 9; ++r) {
            if (tid < 5) {
                int p = d_pairs[r][tid][0], q = d_pairs[r][tid][1];
                if (p > q) { int t = p; p = q; q = t; }
                float app = s_A[p * 10 + p];
                float aqq = s_A[q * 10 + q];
                float apq = s_A[p * 10 + q];
                float c, sn;
                if (fabsf(apq) < 1e-28f) {
                    c = 1.0f; sn = 0.0f;
                } else {
                    float tau = (aqq - app) / (2.0f * apq);
                    float tt = 1.0f / (fabsf(tau) + sqrtf(tau * tau + 1.0f));
                    if (tau < 0.0f) tt = -tt;
                    c = 1.0f / sqrtf(tt * tt + 1.0f);
                    sn = tt * c;
                }
                s_ip[p] = p; s_iq[p] = q; s_cp[p] = c;  s_cq[p] = -sn;
                s_ip[q] = p; s_iq[q] = q; s_cp[q] = sn; s_cq[q] = c;
            }
            __syncthreads();

            float nA0, nU0, nA1 = 0.0f, nU1 = 0.0f;
            {
                int e = tid;
                int i = e / 10, j = e - (e / 10) * 10;
                float wip = s_cp[i], wiq = s_cq[i];
                float wjp = s_cp[j], wjq = s_cq[j];
                int pi_ = s_ip[i], qi_ = s_iq[i];
                int pj  = s_ip[j], qj  = s_iq[j];
                nA0 = wip * (wjp * s_A[pi_ * 10 + pj] + wjq * s_A[pi_ * 10 + qj])
                    + wiq * (wjp * s_A[qi_ * 10 + pj] + wjq * s_A[qi_ * 10 + qj]);
                nU0 = wjp * s_U[i * 10 + pj] + wjq * s_U[i * 10 + qj];
            }
            if (tid < 36) {
                int e = tid + 64;
                int i = e / 10, j = e - (e / 10) * 10;
                float wip = s_cp[i], wiq = s_cq[i];
                float wjp = s_cp[j], wjq = s_cq[j];
                int pi_ = s_ip[i], qi_ = s_iq[i];
                int pj  = s_ip[j], qj  = s_iq[j];
                nA1 = wip * (wjp * s_A[pi_ * 10 + pj] + wjq * s_A[pi_ * 10 + qj])
                    + wiq * (wjp * s_A[qi_ * 10 + pj] + wjq * s_A[qi_ * 10 + qj]);
                nU1 = wjp * s_U[i * 10 + pj] + wjq * s_U[i * 10 + qj];
            }
            __syncthreads();
            s_A[tid] = nA0; s_U[tid] = nU0;
            if (tid < 36) { s_A[tid + 64] = nA1; s_U[tid + 64] = nU1; }
            __syncthreads();
        }
    }

    if (tid < 10) s_lw[tid] = logf(fmaxf(s_A[tid * 11], 1e-4f));
    __syncthreads();

    // Y = U diag(lw) U^T
    {
        int i = tid / 10, j = tid - (tid / 10) * 10;
        float s = 0.0f;
#pragma unroll
        for (int k = 0; k < 10; ++k) s += s_U[i * 10 + k] * s_lw[k] * s_U[j * 10 + k];
        s_Y[tid] = s;
    }
    if (tid < 36) {
        int e = tid + 64;
        int i = e / 10, j = e - (e / 10) * 10;
        float s = 0.0f;
#pragma unroll
        for (int k = 0; k < 10; ++k) s += s_U[i * 10 + k] * s_lw[k] * s_U[j * 10 + k];
        s_Y[e] = s;
    }
    __syncthreads();

    // FC: out[n][o] = sum_k Y[k] * fc_w[o][k] + fc_b[o]
    {
        float s = fcb[tid];
#pragma unroll 4
        for (int k = 0; k < 100; ++k) s += s_Y[k] * s_fcw[k * 65 + tid];
        out[(size_t)n * 64 + tid] = s;
    }
}

// ---------------------------------------------------------------------------
// Fallback (fused, from previous round) in case ws_size is too small.
__global__ __launch_bounds__(1024) void topo_fused(
    const float* __restrict__ x, const float* __restrict__ W1,
    const float* __restrict__ W2, const float* __restrict__ W3,
    const float* __restrict__ fcw, const float* __restrict__ fcb,
    float* __restrict__ out)
{
    __shared__ float s_xm[6400];
    __shared__ float s_mean[32];
    __shared__ float s_w1[500];
    __shared__ float s_w2[300];
    __shared__ float s_w3[152];
    __shared__ float s_t1[375];
    __shared__ float s_wc[250];
    __shared__ float s_E[2560];
    __shared__ float s_A[100];
    __shared__ float s_U[100];
    __shared__ float s_cp[10], s_cq[10];
    __shared__ int   s_ip[10], s_iq[10];
    __shared__ float s_lw[16];
    __shared__ float s_Y[100];
    __shared__ float s_fcw[100 * 65];

    const int tid = threadIdx.x;
    const int n = blockIdx.x;
    const float* xb = x + (size_t)n * (256 * 64 * 25);

    for (int g = tid; g < 6400; g += 1024) {
        int o = g / 100, k = g - o * 100;
        s_fcw[k * 65 + o] = fcw[g];
    }
    for (int g = tid; g < 500; g += 1024) s_w1[g] = W1[g];
    for (int g = tid; g < 300; g += 1024) s_w2[g] = W2[g];
    if (tid < 150) s_w3[tid] = W3[tid];
    for (int g = tid; g < 6400; g += 1024) s_xm[g] = 0.0f;
    __syncthreads();

    {
        const float4* xb4 = reinterpret_cast<const float4*>(xb);
        for (int task = tid; task < 6400; task += 1024) {
            int c = task / 25;
            int m = task - c * 25;
            const float4* p = xb4 + c * 400 + m;
            float s0 = 0.0f, s1 = 0.0f, s2 = 0.0f, s3 = 0.0f;
#pragma unroll
            for (int k = 0; k < 16; ++k) {
                float4 vv = p[25 * k];
                s0 += vv.x; s1 += vv.y; s2 += vv.z; s3 += vv.w;
            }
            int v = (4 * m) % 25;
            int base = c * 25;
            atomicAdd(&s_xm[base + v], s0); v = (v + 1 == 25) ? 0 : v + 1;
            atomicAdd(&s_xm[base + v], s1); v = (v + 1 == 25) ? 0 : v + 1;
            atomicAdd(&s_xm[base + v], s2); v = (v + 1 == 25) ? 0 : v + 1;
            atomicAdd(&s_xm[base + v], s3);
        }
    }
    __syncthreads();

    for (int g = tid; g < 375; g += 1024) {
        int i = g / 15, l = g - i * 15;
        float s = 0.0f;
#pragma unroll
        for (int j = 0; j < 20; ++j) s += s_w1[i * 20 + j] * s_w2[j * 15 + l];
        s_t1[g] = s;
    }
    if (tid < 25) {
        float s = 0.0f;
        for (int c = 0; c < 256; ++c) s += s_xm[c * 25 + tid];
        s_mean[tid] = s * (1.0f / (64.0f * 256.0f));
    }
    __syncthreads();

    for (int g = tid; g < 250; g += 1024) {
        int i = g / 10, m = g - i * 10;
        float s = 0.0f;
#pragma unroll
        for (int l = 0; l < 15; ++l) s += s_t1[i * 15 + l] * s_w3[l * 10 + m];
        s_wc[g] = s;
    }
    for (int o = tid; o < 6400; o += 1024) {
        int v = o - (o / 25) * 25;
        s_xm[o] = s_xm[o] * (1.0f / 64.0f) - s_mean[v];
    }
    __syncthreads();

    for (int idx = tid; idx < 2560; idx += 1024) {
        int c = idx / 10, i = idx - (idx / 10) * 10;
        float s = 0.0f;
#pragma unroll
        for (int v = 0; v < 25; ++v) s += s_xm[c * 25 + v] * s_wc[v * 10 + i];
        s_E[idx] = s;
    }
    __syncthreads();

    if (tid < 55) {
        int i = 0, rem = tid;
        while (rem >= 10 - i) { rem -= 10 - i; ++i; }
        int j = i + rem;
        float s = 0.0f;
        for (int c = 0; c < 256; ++c) s += s_E[c * 10 + i] * s_E[c * 10 + j];
        float wt = 0.0f;
#pragma unroll
        for (int v = 0; v < 25; ++v) wt += s_wc[v * 10 + i] * s_wc[v * 10 + j];
        float m = s * (1.0f / 255.0f) + 1e-8f * wt;
        s_A[i * 10 + j] = m;
        s_A[j * 10 + i] = m;
    }
    if (tid >= 64 && tid < 164) {
        int e = tid - 64;
        s_U[e] = ((e / 10) == (e % 10)) ? 1.0f : 0.0f;
    }
    __syncthreads();

    for (int sweep = 0; sweep < 8; ++sweep) {
        for (int r = 0; r < 9; ++r) {
            if (tid < 5) {
                int p = d_pairs[r][tid][0], q = d_pairs[r][tid][1];
                if (p > q) { int t = p; p = q; q = t; }
                float app = s_A[p * 10 + p];
                float aqq = s_A[q * 10 + q];
                float apq = s_A[p * 10 + q];
                float c, sn;
                if (fabsf(apq) < 1e-28f) {
                    c = 1.0f; sn = 0.0f;
                } else {
                    float tau = (aqq - app) / (2.0f * apq);
                    float tt = 1.0f / (fabsf(tau) + sqrtf(tau * tau + 1.0f));
                    if (tau < 0.0f) tt = -tt;
                    c = 1.0f / sqrtf(tt * tt + 1.0f);
                    sn = tt * c;
                }
                s_ip[p] = p; s_iq[p] = q; s_cp[p] = c;  s_cq[p] = -sn;
                s_ip[q] = p; s_iq[q] = q; s_cp[q] = sn; s_cq[q] = c;
            }
            __syncthreads();
            float newA = 0.0f, newU = 0.0f;
            if (tid < 100) {
                int i = tid / 10, j = tid - (tid / 10) * 10;
                float wip = s_cp[i], wiq = s_cq[i];
                float wjp = s_cp[j], wjq = s_cq[j];
                int pi_ = s_ip[i], qi_ = s_iq[i];
                int pj  = s_ip[j], qj  = s_iq[j];
                newA = wip * (wjp * s_A[pi_ * 10 + pj] + wjq * s_A[pi_ * 10 + qj])
                     + wiq * (wjp * s_A[qi_ * 10 + pj] + wjq * s_A[qi_ * 10 + qj]);
            } else if (tid < 200) {
                int e = tid - 100;
                int i = e / 10, j = e - (e / 10) * 10;
                int pj = s_ip[j], qj = s_iq[j];
                newU = s_cp[j] * s_U[i * 10 + pj] + s_cq[j] * s_U[i * 10 + qj];
            }
            __syncthreads();
            if (tid < 100)      s_A[tid] = newA;
            else if (tid < 200) s_U[tid - 100] = newU;
            __syncthreads();
        }
    }

    if (tid < 10) s_lw[tid] = logf(fmaxf(s_A[tid * 10 + tid], 1e-4f));
    __syncthreads();

    if (tid < 100) {
        int i = tid / 10, j = tid - (tid / 10) * 10;
        float s = 0.0f;
#pragma unroll
        for (int k = 0; k < 10; ++k) s += s_U[i * 10 + k] * s_lw[k] * s_U[j * 10 + k];
        s_Y[tid] = s;
    }
    __syncthreads();

    if (tid < 64) {
        float s = fcb[tid];
#pragma unroll 4
        for (int k = 0; k < 100; ++k) s += s_Y[k] * s_fcw[k * 65 + tid];
        out[(size_t)n * 64 + tid] = s;
    }
}

extern "C" void kernel_launch(void* const* d_in, const int* in_sizes, int n_in,
                              void* d_out, int out_size, void* d_ws, size_t ws_size,
                              hipStream_t stream) {
    const float* x   = (const float*)d_in[0];
    const float* W1  = (const float*)d_in[1];
    const float* W2  = (const float*)d_in[2];
    const float* W3  = (const float*)d_in[3];
    const float* fcw = (const float*)d_in[4];
    const float* fcb = (const float*)d_in[5];
    float* out = (float*)d_out;

    const size_t XSUM_FLOATS = (size_t)65536 * 25;      // 6,553,600 B
    const size_t NEED = (XSUM_FLOATS + 256 * 100) * sizeof(float);

    if (d_ws != nullptr && ws_size >= NEED) {
        float* xsum = (float*)d_ws;
        float* M    = xsum + XSUM_FLOATS;
        k_tsum<<<2048, 256, 0, stream>>>(x, xsum);
        k_cov <<<256, 256, 0, stream>>>(xsum, W1, W2, W3, M);
        k_eig <<<256, 64, 0, stream>>>(M, fcw, fcb, out);
    } else {
        topo_fused<<<256, 1024, 0, stream>>>(x, W1, W2, W3, fcw, fcb, out);
    }
}

// Round 4
// 581.545 us; speedup vs baseline: 1.0607x; 1.0607x over previous
//
#include <hip/hip_runtime.h>
#include <math.h>

// Topology: x(256,256,64,25) -> T-mean -> center over C -> cov(25x25)
// -> bimap W1,W2,W3 (ReEig = identity: eigenvalues >= ~0.0074 >> 1e-4)
// -> logeig(10x10 via Jacobi) -> FC(100->64).
//
// Measured structure of dur_us: ~516us is harness-fixed (2x 1.678GB ws-poison
// fills inside the timed graph at ~6.5TB/s). Controllable kernel time:
// r0=118us, r1=88us, r2=101us. Floor ~= 419MB/6.3TBs + tail ~= 77us.
//
// K1 = per-n stream+cov fused (no xm ws round trip), centering eliminated:
//   F = (xm)@Wc,  Fbar = mean_c F,  M = (sum_c F F^T - C Fbar Fbar^T)/255
//     + 1e-8 Wc^T Wc.
// K2 = per-n single-wave Jacobi + logeig + FC (barriers ~free).

// clang-native vector type: __builtin_nontemporal_load requires a pointer to
// a scalar or clang ext-vector, NOT HIP's float4 class type.
typedef float vfloat4 __attribute__((ext_vector_type(4)));

__device__ __constant__ int d_pairs[9][5][2] = {
    {{9,0},{1,8},{2,7},{3,6},{4,5}},
    {{9,1},{2,0},{3,8},{4,7},{5,6}},
    {{9,2},{3,1},{4,0},{5,8},{6,7}},
    {{9,3},{4,2},{5,1},{6,0},{7,8}},
    {{9,4},{5,3},{6,2},{7,1},{8,0}},
    {{9,5},{6,4},{7,3},{8,2},{0,1}},
    {{9,6},{7,5},{8,4},{0,3},{1,2}},
    {{9,7},{8,6},{0,5},{1,4},{2,3}},
    {{9,8},{0,7},{1,6},{2,5},{3,4}},
};

// ---------------------------------------------------------------------------
// K1: one block per n. Stream x[n] (1.6MB) -> t-sums in LDS -> F -> M -> ws.
__global__ __launch_bounds__(1024) void k_cov1(
    const float* __restrict__ x,
    const float* __restrict__ W1, const float* __restrict__ W2,
    const float* __restrict__ W3, float* __restrict__ Mout)
{
    __shared__ float s_xm[6400];   // [c][v] t-sums (unscaled)
    __shared__ float s_w1[500];
    __shared__ float s_w2[300];
    __shared__ float s_w3[152];
    __shared__ float s_t1[375];    // W1@W2 (25x15)
    __shared__ float s_wc[250];    // W1@W2@W3 (25x10)
    __shared__ float s_F[2560];    // F = xm@Wc (256x10), scaled 1/64
    __shared__ float s_fm[16];     // sum_c F (10 used)
    __shared__ float s_mp[64];     // 55 pair partial sums of FF^T

    const int tid = threadIdx.x;
    const int n = blockIdx.x;

    // ---- zero accumulators, stage weights ----
    for (int g = tid; g < 6400; g += 1024) s_xm[g] = 0.0f;
    if (tid < 500) s_w1[tid] = W1[tid];
    else if (tid < 800) s_w2[tid - 500] = W2[tid - 500];
    else if (tid < 950) s_w3[tid - 800] = W3[tid - 800];
    if (tid < 16) s_fm[tid] = 0.0f;
    if (tid < 64) s_mp[tid] = 0.0f;
    __syncthreads();

    // ---- T1 = W1@W2 ----
    if (tid < 375) {
        int i = tid / 15, l = tid - (tid / 15) * 15;
        float s = 0.0f;
#pragma unroll
        for (int j = 0; j < 20; ++j) s += s_w1[i * 20 + j] * s_w2[j * 15 + l];
        s_t1[tid] = s;
    }
    __syncthreads();

    // ---- Wc = T1@W3 (tid<250) + Phase A streaming (all threads) ----
    if (tid < 250) {
        int i = tid / 10, m = tid - (tid / 10) * 10;
        float s = 0.0f;
#pragma unroll
        for (int l = 0; l < 15; ++l) s += s_t1[i * 15 + l] * s_w3[l * 10 + m];
        s_wc[tid] = s;
    }
    // Phase A: s_xm[c][v] = sum_t x[n][c][t][v].
    // task = c*25 + m (float4 phase). Element e = 4m + 100k + i has FIXED
    // v = (4m+i) mod 25, so 4 register sums -> 4 LDS atomics per task.
    {
        const vfloat4* xb4 = reinterpret_cast<const vfloat4*>(
            x + (size_t)n * (256 * 64 * 25));
        for (int task = tid; task < 6400; task += 1024) {
            int c = task / 25;
            int m = task - c * 25;
            const vfloat4* p = xb4 + c * 400 + m;
            float s0 = 0.0f, s1 = 0.0f, s2 = 0.0f, s3 = 0.0f;
#pragma unroll
            for (int k = 0; k < 16; ++k) {
                vfloat4 vv = __builtin_nontemporal_load(p + 25 * k);
                s0 += vv.x; s1 += vv.y; s2 += vv.z; s3 += vv.w;
            }
            int v = (4 * m) % 25;
            int b = c * 25;
            atomicAdd(&s_xm[b + v], s0); v = (v + 1 == 25) ? 0 : v + 1;
            atomicAdd(&s_xm[b + v], s1); v = (v + 1 == 25) ? 0 : v + 1;
            atomicAdd(&s_xm[b + v], s2); v = (v + 1 == 25) ? 0 : v + 1;
            atomicAdd(&s_xm[b + v], s3);
        }
    }
    __syncthreads();

    // ---- F = (xm/64) @ Wc  (256x10) ----
    for (int idx = tid; idx < 2560; idx += 1024) {
        int c = idx / 10, i = idx - (idx / 10) * 10;
        float s = 0.0f;
#pragma unroll
        for (int v = 0; v < 25; ++v) s += s_xm[c * 25 + v] * s_wc[v * 10 + i];
        s_F[idx] = s * (1.0f / 64.0f);
    }
    __syncthreads();

    // ---- Fbar accumulation: 64 threads per column i ----
    if (tid < 640) {
        int i = tid / 64, c0 = tid - (tid / 64) * 64;
        float s = 0.0f;
#pragma unroll
        for (int k = 0; k < 4; ++k) s += s_F[(c0 + 64 * k) * 10 + i];
        atomicAdd(&s_fm[i], s);
    }
    // ---- M partials: 16 threads per (i,j) pair ----
    if (tid < 880) {
        int pair = tid / 16, part = tid - (tid / 16) * 16;
        int i = 0, rem = pair;
        while (rem >= 10 - i) { rem -= 10 - i; ++i; }
        int j = i + rem;
        float s = 0.0f;
#pragma unroll
        for (int k = 0; k < 16; ++k) {
            int c = part + 16 * k;
            s += s_F[c * 10 + i] * s_F[c * 10 + j];
        }
        atomicAdd(&s_mp[pair], s);
    }
    __syncthreads();

    // ---- finalize M = (sum FF^T - 256 Fbar Fbar^T)/255 + 1e-8 Wc^T Wc ----
    if (tid < 55) {
        int i = 0, rem = tid;
        while (rem >= 10 - i) { rem -= 10 - i; ++i; }
        int j = i + rem;
        float fmi = s_fm[i] * (1.0f / 256.0f);
        float fmj = s_fm[j] * (1.0f / 256.0f);
        float wt = 0.0f;
#pragma unroll
        for (int v = 0; v < 25; ++v) wt += s_wc[v * 10 + i] * s_wc[v * 10 + j];
        float m = (s_mp[tid] - 256.0f * fmi * fmj) * (1.0f / 255.0f) + 1e-8f * wt;
        float* Mn = Mout + (size_t)n * 100;
        Mn[i * 10 + j] = m;
        Mn[j * 10 + i] = m;
    }
}

// ---------------------------------------------------------------------------
// K2: per n (single wave): Jacobi eigensolve of 10x10, logeig, FC(100->64).
__global__ __launch_bounds__(64) void k_eig(
    const float* __restrict__ Min,
    const float* __restrict__ fcw, const float* __restrict__ fcb,
    float* __restrict__ out)
{
    __shared__ float s_A[100];
    __shared__ float s_U[100];
    __shared__ float s_cp[10], s_cq[10];
    __shared__ int   s_ip[10], s_iq[10];
    __shared__ float s_lw[16];
    __shared__ float s_Y[100];
    __shared__ float s_fcw[100 * 65];   // transposed, padded ld=65

    const int tid = threadIdx.x;
    const int n = blockIdx.x;

    // stage fc_w transposed via float4 (row o is 100 floats = 25 float4)
    {
        const float4* fw4 = reinterpret_cast<const float4*>(fcw);
        for (int g4 = tid; g4 < 1600; g4 += 64) {
            float4 w = fw4[g4];
            int o = g4 / 25, k4 = (g4 - o * 25) * 4;
            s_fcw[(k4 + 0) * 65 + o] = w.x;
            s_fcw[(k4 + 1) * 65 + o] = w.y;
            s_fcw[(k4 + 2) * 65 + o] = w.z;
            s_fcw[(k4 + 3) * 65 + o] = w.w;
        }
    }
    const float* Mn = Min + (size_t)n * 100;
    s_A[tid] = Mn[tid];
    if (tid < 36) s_A[tid + 64] = Mn[tid + 64];
    s_U[tid] = ((tid / 10) == (tid % 10)) ? 1.0f : 0.0f;
    if (tid < 36) {
        int e = tid + 64;
        s_U[e] = ((e / 10) == (e % 10)) ? 1.0f : 0.0f;
    }
    __syncthreads();

    // Jacobi (tournament order, 8 sweeps). 1-wave block: barriers are ~free.
    for (int sweep = 0; sweep < 8; ++sweep) {
        for (int r = 0; r < 9; ++r) {
            if (tid < 5) {
                int p = d_pairs[r][tid][0], q = d_pairs[r][tid][1];
                if (p > q) { int t = p; p = q; q = t; }
                float app = s_A[p * 10 + p];
                float aqq = s_A[q * 10 + q];
                float apq = s_A[p * 10 + q];
                float c, sn;
                if (fabsf(apq) < 1e-28f) {
                    c = 1.0f; sn = 0.0f;
                } else {
                    float tau = (aqq - app) / (2.0f * apq);
                    float tt = 1.0f / (fabsf(tau) + sqrtf(tau * tau + 1.0f));
                    if (tau < 0.0f) tt = -tt;
                    c = 1.0f / sqrtf(tt * tt + 1.0f);
                    sn = tt * c;
                }
                s_ip[p] = p; s_iq[p] = q; s_cp[p] = c;  s_cq[p] = -sn;
                s_ip[q] = p; s_iq[q] = q; s_cp[q] = sn; s_cq[q] = c;
            }
            __syncthreads();

            float nA0, nU0, nA1 = 0.0f, nU1 = 0.0f;
            {
                int e = tid;
                int i = e / 10, j = e - (e / 10) * 10;
                float wip = s_cp[i], wiq = s_cq[i];
                float wjp = s_cp[j], wjq = s_cq[j];
                int pi_ = s_ip[i], qi_ = s_iq[i];
                int pj  = s_ip[j], qj  = s_iq[j];
                nA0 = wip * (wjp * s_A[pi_ * 10 + pj] + wjq * s_A[pi_ * 10 + qj])
                    + wiq * (wjp * s_A[qi_ * 10 + pj] + wjq * s_A[qi_ * 10 + qj]);
                nU0 = wjp * s_U[i * 10 + pj] + wjq * s_U[i * 10 + qj];
            }
            if (tid < 36) {
                int e = tid + 64;
                int i = e / 10, j = e - (e / 10) * 10;
                float wip = s_cp[i], wiq = s_cq[i];
                float wjp = s_cp[j], wjq = s_cq[j];
                int pi_ = s_ip[i], qi_ = s_iq[i];
                int pj  = s_ip[j], qj  = s_iq[j];
                nA1 = wip * (wjp * s_A[pi_ * 10 + pj] + wjq * s_A[pi_ * 10 + qj])
                    + wiq * (wjp * s_A[qi_ * 10 + pj] + wjq * s_A[qi_ * 10 + qj]);
                nU1 = wjp * s_U[i * 10 + pj] + wjq * s_U[i * 10 + qj];
            }
            __syncthreads();
            s_A[tid] = nA0; s_U[tid] = nU0;
            if (tid < 36) { s_A[tid + 64] = nA1; s_U[tid + 64] = nU1; }
            __syncthreads();
        }
    }

    if (tid < 10) s_lw[tid] = logf(fmaxf(s_A[tid * 11], 1e-4f));
    __syncthreads();

    // Y = U diag(lw) U^T
    {
        int i = tid / 10, j = tid - (tid / 10) * 10;
        float s = 0.0f;
#pragma unroll
        for (int k = 0; k < 10; ++k) s += s_U[i * 10 + k] * s_lw[k] * s_U[j * 10 + k];
        s_Y[tid] = s;
    }
    if (tid < 36) {
        int e = tid + 64;
        int i = e / 10, j = e - (e / 10) * 10;
        float s = 0.0f;
#pragma unroll
        for (int k = 0; k < 10; ++k) s += s_U[i * 10 + k] * s_lw[k] * s_U[j * 10 + k];
        s_Y[e] = s;
    }
    __syncthreads();

    // FC: out[n][o] = sum_k Y[k] * fc_w[o][k] + fc_b[o]
    {
        float s = fcb[tid];
#pragma unroll 4
        for (int k = 0; k < 100; ++k) s += s_Y[k] * s_fcw[k * 65 + tid];
        out[(size_t)n * 64 + tid] = s;
    }
}

// ---------------------------------------------------------------------------
// Fallback (fused, round-1 version) in case ws_size is too small.
__global__ __launch_bounds__(1024) void topo_fused(
    const float* __restrict__ x, const float* __restrict__ W1,
    const float* __restrict__ W2, const float* __restrict__ W3,
    const float* __restrict__ fcw, const float* __restrict__ fcb,
    float* __restrict__ out)
{
    __shared__ float s_xm[6400];
    __shared__ float s_mean[32];
    __shared__ float s_w1[500];
    __shared__ float s_w2[300];
    __shared__ float s_w3[152];
    __shared__ float s_t1[375];
    __shared__ float s_wc[250];
    __shared__ float s_E[2560];
    __shared__ float s_A[100];
    __shared__ float s_U[100];
    __shared__ float s_cp[10], s_cq[10];
    __shared__ int   s_ip[10], s_iq[10];
    __shared__ float s_lw[16];
    __shared__ float s_Y[100];
    __shared__ float s_fcw[100 * 65];

    const int tid = threadIdx.x;
    const int n = blockIdx.x;
    const float* xb = x + (size_t)n * (256 * 64 * 25);

    for (int g = tid; g < 6400; g += 1024) {
        int o = g / 100, k = g - o * 100;
        s_fcw[k * 65 + o] = fcw[g];
    }
    for (int g = tid; g < 500; g += 1024) s_w1[g] = W1[g];
    for (int g = tid; g < 300; g += 1024) s_w2[g] = W2[g];
    if (tid < 150) s_w3[tid] = W3[tid];
    for (int g = tid; g < 6400; g += 1024) s_xm[g] = 0.0f;
    __syncthreads();

    {
        const float4* xb4 = reinterpret_cast<const float4*>(xb);
        for (int task = tid; task < 6400; task += 1024) {
            int c = task / 25;
            int m = task - c * 25;
            const float4* p = xb4 + c * 400 + m;
            float s0 = 0.0f, s1 = 0.0f, s2 = 0.0f, s3 = 0.0f;
#pragma unroll
            for (int k = 0; k < 16; ++k) {
                float4 vv = p[25 * k];
                s0 += vv.x; s1 += vv.y; s2 += vv.z; s3 += vv.w;
            }
            int v = (4 * m) % 25;
            int base = c * 25;
            atomicAdd(&s_xm[base + v], s0); v = (v + 1 == 25) ? 0 : v + 1;
            atomicAdd(&s_xm[base + v], s1); v = (v + 1 == 25) ? 0 : v + 1;
            atomicAdd(&s_xm[base + v], s2); v = (v + 1 == 25) ? 0 : v + 1;
            atomicAdd(&s_xm[base + v], s3);
        }
    }
    __syncthreads();

    for (int g = tid; g < 375; g += 1024) {
        int i = g / 15, l = g - i * 15;
        float s = 0.0f;
#pragma unroll
        for (int j = 0; j < 20; ++j) s += s_w1[i * 20 + j] * s_w2[j * 15 + l];
        s_t1[g] = s;
    }
    if (tid < 25) {
        float s = 0.0f;
        for (int c = 0; c < 256; ++c) s += s_xm[c * 25 + tid];
        s_mean[tid] = s * (1.0f / (64.0f * 256.0f));
    }
    __syncthreads();

    for (int g = tid; g < 250; g += 1024) {
        int i = g / 10, m = g - i * 10;
        float s = 0.0f;
#pragma unroll
        for (int l = 0; l < 15; ++l) s += s_t1[i * 15 + l] * s_w3[l * 10 + m];
        s_wc[g] = s;
    }
    for (int o = tid; o < 6400; o += 1024) {
        int v = o - (o / 25) * 25;
        s_xm[o] = s_xm[o] * (1.0f / 64.0f) - s_mean[v];
    }
    __syncthreads();

    for (int idx = tid; idx < 2560; idx += 1024) {
        int c = idx / 10, i = idx - (idx / 10) * 10;
        float s = 0.0f;
#pragma unroll
        for (int v = 0; v < 25; ++v) s += s_xm[c * 25 + v] * s_wc[v * 10 + i];
        s_E[idx] = s;
    }
    __syncthreads();

    if (tid < 55) {
        int i = 0, rem = tid;
        while (rem >= 10 - i) { rem -= 10 - i; ++i; }
        int j = i + rem;
        float s = 0.0f;
        for (int c = 0; c < 256; ++c) s += s_E[c * 10 + i] * s_E[c * 10 + j];
        float wt = 0.0f;
#pragma unroll
        for (int v = 0; v < 25; ++v) wt += s_wc[v * 10 + i] * s_wc[v * 10 + j];
        float m = s * (1.0f / 255.0f) + 1e-8f * wt;
        s_A[i * 10 + j] = m;
        s_A[j * 10 + i] = m;
    }
    if (tid >= 64 && tid < 164) {
        int e = tid - 64;
        s_U[e] = ((e / 10) == (e % 10)) ? 1.0f : 0.0f;
    }
    __syncthreads();

    for (int sweep = 0; sweep < 8; ++sweep) {
        for (int r = 0; r < 9; ++r) {
            if (tid < 5) {
                int p = d_pairs[r][tid][0], q = d_pairs[r][tid][1];
                if (p > q) { int t = p; p = q; q = t; }
                float app = s_A[p * 10 + p];
                float aqq = s_A[q * 10 + q];
                float apq = s_A[p * 10 + q];
                float c, sn;
                if (fabsf(apq) < 1e-28f) {
                    c = 1.0f; sn = 0.0f;
                } else {
                    float tau = (aqq - app) / (2.0f * apq);
                    float tt = 1.0f / (fabsf(tau) + sqrtf(tau * tau + 1.0f));
                    if (tau < 0.0f) tt = -tt;
                    c = 1.0f / sqrtf(tt * tt + 1.0f);
                    sn = tt * c;
                }
                s_ip[p] = p; s_iq[p] = q; s_cp[p] = c;  s_cq[p] = -sn;
                s_ip[q] = p; s_iq[q] = q; s_cp[q] = sn; s_cq[q] = c;
            }
            __syncthreads();
            float newA = 0.0f, newU = 0.0f;
            if (tid < 100) {
                int i = tid / 10, j = tid - (tid / 10) * 10;
                float wip = s_cp[i], wiq = s_cq[i];
                float wjp = s_cp[j], wjq = s_cq[j];
                int pi_ = s_ip[i], qi_ = s_iq[i];
                int pj  = s_ip[j], qj  = s_iq[j];
                newA = wip * (wjp * s_A[pi_ * 10 + pj] + wjq * s_A[pi_ * 10 + qj])
                     + wiq * (wjp * s_A[qi_ * 10 + pj] + wjq * s_A[qi_ * 10 + qj]);
            } else if (tid < 200) {
                int e = tid - 100;
                int i = e / 10, j = e - (e / 10) * 10;
                int pj = s_ip[j], qj = s_iq[j];
                newU = s_cp[j] * s_U[i * 10 + pj] + s_cq[j] * s_U[i * 10 + qj];
            }
            __syncthreads();
            if (tid < 100)      s_A[tid] = newA;
            else if (tid < 200) s_U[tid - 100] = newU;
            __syncthreads();
        }
    }

    if (tid < 10) s_lw[tid] = logf(fmaxf(s_A[tid * 10 + tid], 1e-4f));
    __syncthreads();

    if (tid < 100) {
        int i = tid / 10, j = tid - (tid / 10) * 10;
        float s = 0.0f;
#pragma unroll
        for (int k = 0; k < 10; ++k) s += s_U[i * 10 + k] * s_lw[k] * s_U[j * 10 + k];
        s_Y[tid] = s;
    }
    __syncthreads();

    if (tid < 64) {
        float s = fcb[tid];
#pragma unroll 4
        for (int k = 0; k < 100; ++k) s += s_Y[k] * s_fcw[k * 65 + tid];
        out[(size_t)n * 64 + tid] = s;
    }
}

extern "C" void kernel_launch(void* const* d_in, const int* in_sizes, int n_in,
                              void* d_out, int out_size, void* d_ws, size_t ws_size,
                              hipStream_t stream) {
    const float* x   = (const float*)d_in[0];
    const float* W1  = (const float*)d_in[1];
    const float* W2  = (const float*)d_in[2];
    const float* W3  = (const float*)d_in[3];
    const float* fcw = (const float*)d_in[4];
    const float* fcb = (const float*)d_in[5];
    float* out = (float*)d_out;

    const size_t NEED = (size_t)256 * 100 * sizeof(float);   // 102.4 KB

    if (d_ws != nullptr && ws_size >= NEED) {
        float* M = (float*)d_ws;
        k_cov1<<<256, 1024, 0, stream>>>(x, W1, W2, W3, M);
        k_eig <<<256, 64, 0, stream>>>(M, fcw, fcb, out);
    } else {
        topo_fused<<<256, 1024, 0, stream>>>(x, W1, W2, W3, fcw, fcb, out);
    }
}